// Round 16
// baseline (2339.368 us; speedup 1.0000x reference)
//
#include <hip/hip_runtime.h>
#include <hip/hip_bf16.h>

#define TQ_D   1024
#define TQ_KC  16
#define MERGE_K 512          // OpenBLAS KC-panel boundary (proven R9)

// ---- panel GEMM tile ----
#define BM     128
#define BN     64
#define BK     32
#define NT_HALF (MERGE_K / BK)   // 16 k-tiles per panel
#define LDA    (BM + 4)      // 132
#define LDB    (BN + 4)      // 68

// ---------------------------------------------------------------------------
// Panel kernel: BOTH 512-wide panels in one dispatch (blockIdx.z = panel).
// Each block: one 128x64 tile of one panel, single 32-reg accumulator,
// serial ascending-k f32 FMA chain per element (exact R9 realization).
// Raw f32 partials: panel 0 -> P1 (oidx region), panel 1 -> P2 (xhat region).
// ---------------------------------------------------------------------------
__global__ __launch_bounds__(256, 4)
void tq_panel2(const float* __restrict__ X,
               const float* __restrict__ Pi,
               float* __restrict__ P1,
               float* __restrict__ P2)
{
    __shared__ float As[BK][LDA];
    __shared__ float Bs[BK][LDB];

    const int tid = threadIdx.x;
    const int m0 = blockIdx.y * BM;
    const int n0 = blockIdx.x * BN;
    const int k0 = blockIdx.z * MERGE_K;
    float* Pz = blockIdx.z ? P2 : P1;

    const int tx = tid & 15;
    const int ty = tid >> 4;

    // staging maps (BK=32)
    const int ar = tid >> 1;          // A row 0..127
    const int ac = (tid & 1) * 16;    // A k-base 0/16
    const int bn = tid >> 2;          // B row(n) 0..63
    const int bc = (tid & 3) * 8;     // B k-base 0/8/16/24

    const float* aPtr = X  + (size_t)(m0 + ar) * TQ_D + k0 + ac;
    const float* bPtr = Pi + (size_t)(n0 + bn) * TQ_D + k0 + bc;

    float acc[2][4][4];
#pragma unroll
    for (int r = 0; r < 2; ++r)
#pragma unroll
        for (int i = 0; i < 4; ++i)
#pragma unroll
            for (int j = 0; j < 4; ++j) acc[r][i][j] = 0.0f;

    // prefetch + stage tile 0
    float4 va[4], vb[2];
#pragma unroll
    for (int q = 0; q < 4; ++q) va[q] = *(const float4*)(aPtr + 4 * q);
#pragma unroll
    for (int q = 0; q < 2; ++q) vb[q] = *(const float4*)(bPtr + 4 * q);
#pragma unroll
    for (int q = 0; q < 4; ++q)
#pragma unroll
        for (int e = 0; e < 4; ++e)
            As[ac + 4 * q + e][ar] = ((const float*)&va[q])[e];
#pragma unroll
    for (int q = 0; q < 2; ++q)
#pragma unroll
        for (int e = 0; e < 4; ++e)
            Bs[bc + 4 * q + e][bn] = ((const float*)&vb[q])[e];
    __syncthreads();

    for (int kt = 0; kt < NT_HALF; ++kt) {
        const bool more = (kt + 1) < NT_HALF;
        if (more) {
            const float* ap = aPtr + (kt + 1) * BK;
            const float* bp = bPtr + (kt + 1) * BK;
#pragma unroll
            for (int q = 0; q < 4; ++q) va[q] = *(const float4*)(ap + 4 * q);
#pragma unroll
            for (int q = 0; q < 2; ++q) vb[q] = *(const float4*)(bp + 4 * q);
        }
#pragma unroll
        for (int k = 0; k < BK; ++k) {
            const float4 a0 = *(const float4*)&As[k][ty << 2];
            const float4 a1 = *(const float4*)&As[k][64 + (ty << 2)];
            const float4 b0 = *(const float4*)&Bs[k][tx << 2];
            const float a0v[4] = {a0.x, a0.y, a0.z, a0.w};
            const float a1v[4] = {a1.x, a1.y, a1.z, a1.w};
            const float bv[4]  = {b0.x, b0.y, b0.z, b0.w};
#pragma unroll
            for (int i = 0; i < 4; ++i)
#pragma unroll
                for (int j = 0; j < 4; ++j) {
                    acc[0][i][j] = fmaf(a0v[i], bv[j], acc[0][i][j]);
                    acc[1][i][j] = fmaf(a1v[i], bv[j], acc[1][i][j]);
                }
        }
        if (more) {
            __syncthreads();
#pragma unroll
            for (int q = 0; q < 4; ++q)
#pragma unroll
                for (int e = 0; e < 4; ++e)
                    As[ac + 4 * q + e][ar] = ((const float*)&va[q])[e];
#pragma unroll
            for (int q = 0; q < 2; ++q)
#pragma unroll
                for (int e = 0; e < 4; ++e)
                    Bs[bc + 4 * q + e][bn] = ((const float*)&vb[q])[e];
            __syncthreads();
        }
    }

    // store raw partials
#pragma unroll
    for (int r = 0; r < 2; ++r)
#pragma unroll
        for (int i = 0; i < 4; ++i) {
            const int m = m0 + (r << 6) + (ty << 2) + i;
            *(float4*)(Pz + (size_t)m * TQ_D + n0 + (tx << 2)) =
                make_float4(acc[r][i][0], acc[r][i][1], acc[r][i][2], acc[r][i][3]);
        }
}

// ---------------------------------------------------------------------------
// Merge: y = p1 + p2 (the exact single R9 panel-merge f32 add), then literal
// f32 argmin (first strict min). In-place over P1 -> indices (as float).
// ---------------------------------------------------------------------------
__global__ __launch_bounds__(256)
void tq_merge(float* __restrict__ P1,
              const float* __restrict__ P2,
              const float* __restrict__ Cent,
              int total4)
{
    const int e4 = blockIdx.x * 256 + threadIdx.x;
    if (e4 >= total4) return;

    float c[TQ_KC];
#pragma unroll
    for (int q = 0; q < TQ_KC; ++q) c[q] = Cent[q];

    const float4 p1 = *((const float4*)P1 + e4);
    const float4 p2 = *((const float4*)P2 + e4);
    const float y4[4] = {p1.x + p2.x, p1.y + p2.y, p1.z + p2.z, p1.w + p2.w};
    float o[4];
#pragma unroll
    for (int j = 0; j < 4; ++j) {
        const float y = y4[j];
        int best = 0;
        float bd = fabsf(y - c[0]);
#pragma unroll
        for (int q = 1; q < TQ_KC; ++q) {
            const float d = fabsf(y - c[q]);
            if (d < bd) { bd = d; best = q; }
        }
        o[j] = (float)best;
    }
    *((float4*)P1 + e4) = make_float4(o[0], o[1], o[2], o[3]);
}

// ---------------------------------------------------------------------------
// Kernel 2 (MFMA, proven R15): x_hat = dequant(idx) @ Pi, bf16 MFMA f32-acc.
// Overwrites the P2 scratch (xhat region) with the real output.
// ---------------------------------------------------------------------------
typedef __attribute__((ext_vector_type(8))) short bf16x8;
typedef __attribute__((ext_vector_type(4))) float f32x4;

__device__ __forceinline__ unsigned short f2bf(float f) {
    union { __hip_bfloat16 h; unsigned short s; } u;
    u.h = __float2bfloat16(f);
    return u.s;
}

__global__ __launch_bounds__(256)
void tq_dq_mfma(const float* __restrict__ IdxF,
                const float* __restrict__ Pi,
                const float* __restrict__ Cent,
                float* __restrict__ Xhat)
{
    __shared__ unsigned short Ys[128][40];
    __shared__ unsigned short Ps[128][40];
    __shared__ unsigned short csb[TQ_KC];

    const int tid  = threadIdx.x;
    const int lane = tid & 63;
    const int wv   = tid >> 6;
    const int m0 = blockIdx.y * 128;
    const int n0 = blockIdx.x * 128;
    const int wr = (wv >> 1) * 64;
    const int wc = (wv & 1) * 64;
    const int l15 = lane & 15;
    const int k8  = (lane >> 4) * 8;

    const int arow = tid >> 1;
    const int acol = (tid & 1) * 16;
    const int bn   = tid & 127;
    const int bkq  = (tid >> 7) * 16;

    const float* aP = IdxF + (size_t)(m0 + arow) * TQ_D + acol;
    const float* bP = Pi + (size_t)bkq * TQ_D + n0 + bn;

    if (tid < TQ_KC) csb[tid] = f2bf(Cent[tid]);

    f32x4 acc[4][4];
#pragma unroll
    for (int i = 0; i < 4; ++i)
#pragma unroll
        for (int j = 0; j < 4; ++j)
#pragma unroll
            for (int r = 0; r < 4; ++r) acc[i][j][r] = 0.0f;

    float4 va[4];
    float  vb[16];
#pragma unroll
    for (int q = 0; q < 4; ++q) va[q] = *(const float4*)(aP + 4 * q);
#pragma unroll
    for (int k = 0; k < 16; ++k) vb[k] = bP[(size_t)k * TQ_D];

    __syncthreads();   // csb ready

#pragma unroll
    for (int q = 0; q < 4; ++q) {
        ushort4 w;
        w.x = csb[(int)va[q].x & 15];
        w.y = csb[(int)va[q].y & 15];
        w.z = csb[(int)va[q].z & 15];
        w.w = csb[(int)va[q].w & 15];
        *(ushort4*)&Ys[arow][acol + 4 * q] = w;
    }
#pragma unroll
    for (int k = 0; k < 16; ++k) Ps[bn][bkq + k] = f2bf(vb[k]);
    __syncthreads();

    for (int kt = 0; kt < 32; ++kt) {
        const bool more = (kt + 1) < 32;
        if (more) {
            const float* ap = aP + (kt + 1) * 32;
            const float* bp = bP + (size_t)(kt + 1) * 32 * TQ_D;
#pragma unroll
            for (int q = 0; q < 4; ++q) va[q] = *(const float4*)(ap + 4 * q);
#pragma unroll
            for (int k = 0; k < 16; ++k) vb[k] = bp[(size_t)k * TQ_D];
        }

        bf16x8 af[4], bfr[4];
#pragma unroll
        for (int i = 0; i < 4; ++i)
            af[i] = *(const bf16x8*)&Ys[wr + i * 16 + l15][k8];
#pragma unroll
        for (int j = 0; j < 4; ++j)
            bfr[j] = *(const bf16x8*)&Ps[wc + j * 16 + l15][k8];

#pragma unroll
        for (int i = 0; i < 4; ++i)
#pragma unroll
            for (int j = 0; j < 4; ++j)
                acc[i][j] = __builtin_amdgcn_mfma_f32_16x16x32_bf16(
                    af[i], bfr[j], acc[i][j], 0, 0, 0);

        if (more) {
            __syncthreads();
#pragma unroll
            for (int q = 0; q < 4; ++q) {
                ushort4 w;
                w.x = csb[(int)va[q].x & 15];
                w.y = csb[(int)va[q].y & 15];
                w.z = csb[(int)va[q].z & 15];
                w.w = csb[(int)va[q].w & 15];
                *(ushort4*)&Ys[arow][acol + 4 * q] = w;
            }
#pragma unroll
            for (int k = 0; k < 16; ++k) Ps[bn][bkq + k] = f2bf(vb[k]);
            __syncthreads();
        }
    }

#pragma unroll
    for (int i = 0; i < 4; ++i)
#pragma unroll
        for (int j = 0; j < 4; ++j)
#pragma unroll
            for (int r = 0; r < 4; ++r) {
                const int row = wr + i * 16 + (lane >> 4) * 4 + r;
                const int col = wc + j * 16 + l15;
                Xhat[(size_t)(m0 + row) * TQ_D + n0 + col] = acc[i][j][r];
            }
}

// ---------------------------------------------------------------------------
extern "C" void kernel_launch(void* const* d_in, const int* in_sizes, int n_in,
                              void* d_out, int out_size, void* d_ws, size_t ws_size,
                              hipStream_t stream)
{
    const float* x    = (const float*)d_in[0];   // [N, 1024]
    const float* Pi   = (const float*)d_in[1];   // [1024, 1024]
    const float* cent = (const float*)d_in[2];   // [16]
    float* out = (float*)d_out;

    const int ND = in_sizes[0];      // N * 1024
    const int N  = ND / TQ_D;        // 4096

    float* xhat = out;               // output 0 (+ panel-2 scratch)
    float* oidx = out + ND;          // output 1 (+ panel-1 scratch)

    // Pass 1: both panels concurrently (1024 blocks = 4/CU).
    dim3 grid1(TQ_D / BN, N / BM, 2);    // (16, 32, 2)
    tq_panel2<<<grid1, 256, 0, stream>>>(x, Pi, oidx, xhat);

    // Pass 2: merge + argmin -> indices (in-place over panel-1 partials).
    tq_merge<<<(ND / 4 + 255) / 256, 256, 0, stream>>>(oidx, xhat, cent, ND / 4);

    // Pass 3: dequant + unrotate (MFMA), overwrites xhat scratch.
    dim3 grid3(TQ_D / 128, N / 128);     // (8, 32)
    tq_dq_mfma<<<grid3, 256, 0, stream>>>(oidx, Pi, cent, xhat);
}

// Round 17
// 180.351 us; speedup vs baseline: 12.9712x; 12.9712x over previous
//
#include <hip/hip_runtime.h>
#include <hip/hip_bf16.h>

#define TQ_D   1024
#define TQ_KC  16
#define MERGE_K 512          // OpenBLAS KC-panel boundary (proven R9)

// ---- panel GEMM tile (R15-proven body: BK=16, ~128 VGPR, no spill) ----
#define BM     128
#define BN     64
#define BK     16
#define NT_HALF (MERGE_K / BK)   // 32 k-tiles per panel
#define LDA    (BM + 4)      // 132
#define LDB    (BN + 4)      // 68

// ---------------------------------------------------------------------------
// Panel kernel: BOTH 512-wide panels in one dispatch (blockIdx.z = panel).
// Each block: one 128x64 tile of one panel, single 32-reg accumulator,
// serial ascending-k f32 FMA chain per element (exact R9 realization).
// Raw f32 partials: panel 0 -> P1 (oidx region), panel 1 -> P2 (xhat region).
// __launch_bounds__(256,2): VGPR cap 256 (lands ~128 like R14/R15) — the
// (256,4) cap in R16 forced 64 VGPRs and catastrophic spill.
// ---------------------------------------------------------------------------
__global__ __launch_bounds__(256, 2)
void tq_panel2(const float* __restrict__ X,
               const float* __restrict__ Pi,
               float* __restrict__ P1,
               float* __restrict__ P2)
{
    __shared__ float As[BK][LDA];
    __shared__ float Bs[BK][LDB];

    const int tid = threadIdx.x;
    const int m0 = blockIdx.y * BM;
    const int n0 = blockIdx.x * BN;
    const int k0 = blockIdx.z * MERGE_K;
    float* Pz = blockIdx.z ? P2 : P1;

    const int tx = tid & 15;
    const int ty = tid >> 4;

    const int rr = tid >> 2;   // staging row 0..63
    const int cc = tid & 3;    // staging k-quad

    const float* aPtr = X  + (size_t)(m0 + rr) * TQ_D + k0 + (cc << 2);
    const float* bPtr = Pi + (size_t)(n0 + rr) * TQ_D + k0 + (cc << 2);

    float acc[2][4][4];
#pragma unroll
    for (int r = 0; r < 2; ++r)
#pragma unroll
        for (int i = 0; i < 4; ++i)
#pragma unroll
            for (int j = 0; j < 4; ++j) acc[r][i][j] = 0.0f;

    // stage tile 0 (R15 mapping: 12 staging regs)
    float4 va0 = *(const float4*)(aPtr);
    float4 va1 = *(const float4*)(aPtr + (size_t)64 * TQ_D);
    float4 vb0 = *(const float4*)(bPtr);
#pragma unroll
    for (int q = 0; q < 4; ++q) {
        As[(cc << 2) + q][rr]      = ((const float*)&va0)[q];
        As[(cc << 2) + q][rr + 64] = ((const float*)&va1)[q];
        Bs[(cc << 2) + q][rr]      = ((const float*)&vb0)[q];
    }
    __syncthreads();

    for (int kt = 0; kt < NT_HALF; ++kt) {
        const bool more = (kt + 1) < NT_HALF;
        if (more) {
            const float* ap = aPtr + (kt + 1) * BK;
            const float* bp = bPtr + (kt + 1) * BK;
            va0 = *(const float4*)(ap);
            va1 = *(const float4*)(ap + (size_t)64 * TQ_D);
            vb0 = *(const float4*)(bp);
        }
#pragma unroll
        for (int k = 0; k < BK; ++k) {
            const float4 a0 = *(const float4*)&As[k][ty << 2];
            const float4 a1 = *(const float4*)&As[k][64 + (ty << 2)];
            const float4 b0 = *(const float4*)&Bs[k][tx << 2];
            const float a0v[4] = {a0.x, a0.y, a0.z, a0.w};
            const float a1v[4] = {a1.x, a1.y, a1.z, a1.w};
            const float bv[4]  = {b0.x, b0.y, b0.z, b0.w};
#pragma unroll
            for (int i = 0; i < 4; ++i)
#pragma unroll
                for (int j = 0; j < 4; ++j) {
                    acc[0][i][j] = fmaf(a0v[i], bv[j], acc[0][i][j]);
                    acc[1][i][j] = fmaf(a1v[i], bv[j], acc[1][i][j]);
                }
        }
        if (more) {
            __syncthreads();
#pragma unroll
            for (int q = 0; q < 4; ++q) {
                As[(cc << 2) + q][rr]      = ((const float*)&va0)[q];
                As[(cc << 2) + q][rr + 64] = ((const float*)&va1)[q];
                Bs[(cc << 2) + q][rr]      = ((const float*)&vb0)[q];
            }
            __syncthreads();
        }
    }

    // store raw partials
#pragma unroll
    for (int r = 0; r < 2; ++r)
#pragma unroll
        for (int i = 0; i < 4; ++i) {
            const int m = m0 + (r << 6) + (ty << 2) + i;
            *(float4*)(Pz + (size_t)m * TQ_D + n0 + (tx << 2)) =
                make_float4(acc[r][i][0], acc[r][i][1], acc[r][i][2], acc[r][i][3]);
        }
}

// ---------------------------------------------------------------------------
// Merge: y = p1 + p2 (the exact single R9 panel-merge f32 add), then literal
// f32 argmin (first strict min). In-place over P1 -> indices (as float).
// ---------------------------------------------------------------------------
__global__ __launch_bounds__(256)
void tq_merge(float* __restrict__ P1,
              const float* __restrict__ P2,
              const float* __restrict__ Cent,
              int total4)
{
    const int e4 = blockIdx.x * 256 + threadIdx.x;
    if (e4 >= total4) return;

    float c[TQ_KC];
#pragma unroll
    for (int q = 0; q < TQ_KC; ++q) c[q] = Cent[q];

    const float4 p1 = *((const float4*)P1 + e4);
    const float4 p2 = *((const float4*)P2 + e4);
    const float y4[4] = {p1.x + p2.x, p1.y + p2.y, p1.z + p2.z, p1.w + p2.w};
    float o[4];
#pragma unroll
    for (int j = 0; j < 4; ++j) {
        const float y = y4[j];
        int best = 0;
        float bd = fabsf(y - c[0]);
#pragma unroll
        for (int q = 1; q < TQ_KC; ++q) {
            const float d = fabsf(y - c[q]);
            if (d < bd) { bd = d; best = q; }
        }
        o[j] = (float)best;
    }
    *((float4*)P1 + e4) = make_float4(o[0], o[1], o[2], o[3]);
}

// ---------------------------------------------------------------------------
// Kernel 2 (MFMA, proven R15): x_hat = dequant(idx) @ Pi, bf16 MFMA f32-acc.
// Overwrites the P2 scratch (xhat region) with the real output.
// ---------------------------------------------------------------------------
typedef __attribute__((ext_vector_type(8))) short bf16x8;
typedef __attribute__((ext_vector_type(4))) float f32x4;

__device__ __forceinline__ unsigned short f2bf(float f) {
    union { __hip_bfloat16 h; unsigned short s; } u;
    u.h = __float2bfloat16(f);
    return u.s;
}

__global__ __launch_bounds__(256)
void tq_dq_mfma(const float* __restrict__ IdxF,
                const float* __restrict__ Pi,
                const float* __restrict__ Cent,
                float* __restrict__ Xhat)
{
    __shared__ unsigned short Ys[128][40];
    __shared__ unsigned short Ps[128][40];
    __shared__ unsigned short csb[TQ_KC];

    const int tid  = threadIdx.x;
    const int lane = tid & 63;
    const int wv   = tid >> 6;
    const int m0 = blockIdx.y * 128;
    const int n0 = blockIdx.x * 128;
    const int wr = (wv >> 1) * 64;
    const int wc = (wv & 1) * 64;
    const int l15 = lane & 15;
    const int k8  = (lane >> 4) * 8;

    const int arow = tid >> 1;
    const int acol = (tid & 1) * 16;
    const int bn   = tid & 127;
    const int bkq  = (tid >> 7) * 16;

    const float* aP = IdxF + (size_t)(m0 + arow) * TQ_D + acol;
    const float* bP = Pi + (size_t)bkq * TQ_D + n0 + bn;

    if (tid < TQ_KC) csb[tid] = f2bf(Cent[tid]);

    f32x4 acc[4][4];
#pragma unroll
    for (int i = 0; i < 4; ++i)
#pragma unroll
        for (int j = 0; j < 4; ++j)
#pragma unroll
            for (int r = 0; r < 4; ++r) acc[i][j][r] = 0.0f;

    float4 va[4];
    float  vb[16];
#pragma unroll
    for (int q = 0; q < 4; ++q) va[q] = *(const float4*)(aP + 4 * q);
#pragma unroll
    for (int k = 0; k < 16; ++k) vb[k] = bP[(size_t)k * TQ_D];

    __syncthreads();   // csb ready

#pragma unroll
    for (int q = 0; q < 4; ++q) {
        ushort4 w;
        w.x = csb[(int)va[q].x & 15];
        w.y = csb[(int)va[q].y & 15];
        w.z = csb[(int)va[q].z & 15];
        w.w = csb[(int)va[q].w & 15];
        *(ushort4*)&Ys[arow][acol + 4 * q] = w;
    }
#pragma unroll
    for (int k = 0; k < 16; ++k) Ps[bn][bkq + k] = f2bf(vb[k]);
    __syncthreads();

    for (int kt = 0; kt < 32; ++kt) {
        const bool more = (kt + 1) < 32;
        if (more) {
            const float* ap = aP + (kt + 1) * 32;
            const float* bp = bP + (size_t)(kt + 1) * 32 * TQ_D;
#pragma unroll
            for (int q = 0; q < 4; ++q) va[q] = *(const float4*)(ap + 4 * q);
#pragma unroll
            for (int k = 0; k < 16; ++k) vb[k] = bp[(size_t)k * TQ_D];
        }

        bf16x8 af[4], bfr[4];
#pragma unroll
        for (int i = 0; i < 4; ++i)
            af[i] = *(const bf16x8*)&Ys[wr + i * 16 + l15][k8];
#pragma unroll
        for (int j = 0; j < 4; ++j)
            bfr[j] = *(const bf16x8*)&Ps[wc + j * 16 + l15][k8];

#pragma unroll
        for (int i = 0; i < 4; ++i)
#pragma unroll
            for (int j = 0; j < 4; ++j)
                acc[i][j] = __builtin_amdgcn_mfma_f32_16x16x32_bf16(
                    af[i], bfr[j], acc[i][j], 0, 0, 0);

        if (more) {
            __syncthreads();
#pragma unroll
            for (int q = 0; q < 4; ++q) {
                ushort4 w;
                w.x = csb[(int)va[q].x & 15];
                w.y = csb[(int)va[q].y & 15];
                w.z = csb[(int)va[q].z & 15];
                w.w = csb[(int)va[q].w & 15];
                *(ushort4*)&Ys[arow][acol + 4 * q] = w;
            }
#pragma unroll
            for (int k = 0; k < 16; ++k) Ps[bn][bkq + k] = f2bf(vb[k]);
            __syncthreads();
        }
    }

#pragma unroll
    for (int i = 0; i < 4; ++i)
#pragma unroll
        for (int j = 0; j < 4; ++j)
#pragma unroll
            for (int r = 0; r < 4; ++r) {
                const int row = wr + i * 16 + (lane >> 4) * 4 + r;
                const int col = wc + j * 16 + l15;
                Xhat[(size_t)(m0 + row) * TQ_D + n0 + col] = acc[i][j][r];
            }
}

// ---------------------------------------------------------------------------
extern "C" void kernel_launch(void* const* d_in, const int* in_sizes, int n_in,
                              void* d_out, int out_size, void* d_ws, size_t ws_size,
                              hipStream_t stream)
{
    const float* x    = (const float*)d_in[0];   // [N, 1024]
    const float* Pi   = (const float*)d_in[1];   // [1024, 1024]
    const float* cent = (const float*)d_in[2];   // [16]
    float* out = (float*)d_out;

    const int ND = in_sizes[0];      // N * 1024
    const int N  = ND / TQ_D;        // 4096

    float* xhat = out;               // output 0 (+ panel-2 scratch)
    float* oidx = out + ND;          // output 1 (+ panel-1 scratch)

    // Pass 1: both panels concurrently (1024 blocks).
    dim3 grid1(TQ_D / BN, N / BM, 2);    // (16, 32, 2)
    tq_panel2<<<grid1, 256, 0, stream>>>(x, Pi, oidx, xhat);

    // Pass 2: merge + argmin -> indices (in-place over panel-1 partials).
    tq_merge<<<(ND / 4 + 255) / 256, 256, 0, stream>>>(oidx, xhat, cent, ND / 4);

    // Pass 3: dequant + unrotate (MFMA), overwrites xhat scratch.
    dim3 grid3(TQ_D / 128, N / 128);     // (8, 32)
    tq_dq_mfma<<<grid3, 256, 0, stream>>>(oidx, Pi, cent, xhat);
}